// Round 1
// baseline (146.656 us; speedup 1.0000x reference)
//
#include <hip/hip_runtime.h>
#include <hip/hip_bf16.h>

#define TT 16384
#define DD 2048
#define EE 64

// ---------------------------------------------------------------------------
// Kernel A: partial gate GEMM.  grid = 64 token-blocks * dsplit, block = 256.
// Wave w handles experts [w*16, w*16+16); lane handles tokens {m*64+lane}.
// x chunk staged in XOR-swizzled LDS (64KB, conflict-free ds_read_b128);
// W rows are wave-uniform loads (scalar-cache).  acc[4][16] fp32 in VGPRs.
// Accumulation order is fixed (d ascending within slice) -> deterministic.
__global__ __launch_bounds__(256, 2)
void gate_partial(const float* __restrict__ x, const float* __restrict__ wg,
                  float* __restrict__ part, int ds_shift) {
    const int dsplit_m1 = (1 << ds_shift) - 1;
    const int tb = (int)blockIdx.x >> ds_shift;       // token block 0..63
    const int ds = (int)blockIdx.x & dsplit_m1;       // d-slice index
    const int dslice = DD >> ds_shift;                // 256 at dsplit=8
    const int d0 = ds * dslice;
    const int tid = threadIdx.x;
    const int lane = tid & 63;
    const int ebase = __builtin_amdgcn_readfirstlane((tid >> 6) * 16);

    __shared__ float lx[256][64];   // exactly 64 KB, XOR-swizzled columns

    float acc[4][16];
#pragma unroll
    for (int m = 0; m < 4; ++m)
#pragma unroll
        for (int e = 0; e < 16; ++e) acc[m][e] = 0.0f;

    const int srow = tid >> 4;              // staging row base 0..15
    const int scolk = tid & 15;             // float4 column index
    const int swz = scolk ^ (srow & 7);     // swizzled write column
    const int rsw = lane & 7;               // read-side row&7 (m*64 keeps it)
    const float* xbase = x + (size_t)(tb * 256) * DD + d0;

    for (int cb = 0; cb < dslice; cb += 64) {
        __syncthreads();  // protect lx from previous chunk's readers
#pragma unroll
        for (int p = 0; p < 16; ++p) {
            const int row = srow + p * 16;  // row&7 == srow&7 (p*16 % 8 == 0)
            const float4 v = *reinterpret_cast<const float4*>(
                xbase + (size_t)row * DD + (cb + scolk * 4));
            *reinterpret_cast<float4*>(&lx[row][swz * 4]) = v;
        }
        __syncthreads();
#pragma unroll 2
        for (int d4 = 0; d4 < 64; d4 += 4) {
            float4 xv[4];
            const int rk = (d4 >> 2) ^ rsw;
#pragma unroll
            for (int m = 0; m < 4; ++m)
                xv[m] = *reinterpret_cast<const float4*>(&lx[m * 64 + lane][rk * 4]);
#pragma unroll
            for (int j = 0; j < 4; ++j) {
                const float* wr = wg + (size_t)(d0 + cb + d4 + j) * EE + ebase;
                float4 wq[4];
#pragma unroll
                for (int q = 0; q < 4; ++q)
                    wq[q] = *reinterpret_cast<const float4*>(wr + q * 4);
#pragma unroll
                for (int m = 0; m < 4; ++m) {
                    const float xs = reinterpret_cast<const float*>(&xv[m])[j];
#pragma unroll
                    for (int ei = 0; ei < 16; ++ei) {
                        const float wv =
                            reinterpret_cast<const float*>(&wq[ei >> 2])[ei & 3];
                        acc[m][ei] = fmaf(xs, wv, acc[m][ei]);
                    }
                }
            }
        }
    }
    // part[ds][e][t]  (t contiguous across lanes -> coalesced stores)
    float* pb = part + (size_t)ds * EE * TT;
#pragma unroll
    for (int ei = 0; ei < 16; ++ei) {
        const int eg = ebase + ei;
#pragma unroll
        for (int m = 0; m < 4; ++m) {
            const int t = tb * 256 + m * 64 + lane;
            pb[(size_t)eg * TT + t] = acc[m][ei];
        }
    }
}

// ---------------------------------------------------------------------------
// Kernel B: sum partials -> logits[64] per token, biased top-2 (strict '>'
// keeps the lower index on ties, matching jax.lax.top_k), softmax over the
// UNBIASED selected logits, write weights + indices, per-block expert bins
// (single wave -> deterministic LDS-atomic order).
__global__ __launch_bounds__(64)
void reduce_topk(const float* __restrict__ part, const float* __restrict__ loads,
                 float* __restrict__ out, float* __restrict__ binpart, int dsplit) {
    const int lane = threadIdx.x;
    const int t = (int)blockIdx.x * 64 + lane;

    float logits[64];
#pragma unroll
    for (int e = 0; e < 64; ++e) logits[e] = 0.0f;
    for (int ds = 0; ds < dsplit; ++ds) {
        const float* pb = part + (size_t)ds * EE * TT + t;
#pragma unroll
        for (int e = 0; e < 64; ++e) logits[e] += pb[(size_t)e * TT];
    }

    float bv1 = -3.0e38f, uv1 = 0.0f, bv2 = -3.0e38f, uv2 = 0.0f;
    int i1 = 0, i2 = 0;
#pragma unroll
    for (int e = 0; e < 64; ++e) {
        const float u = logits[e];
        const float b = u - (loads[e] - 0.015625f) * 2.0f;  // + bias[e]
        if (b > bv1) {
            bv2 = bv1; uv2 = uv1; i2 = i1;
            bv1 = b;   uv1 = u;   i1 = e;
        } else if (b > bv2) {
            bv2 = b; uv2 = u; i2 = e;
        }
    }
    const float mx = fmaxf(uv1, uv2);
    const float e1 = __expf(uv1 - mx), e2 = __expf(uv2 - mx);
    const float inv = 1.0f / (e1 + e2);
    const float w1 = e1 * inv, w2 = e2 * inv;

    *reinterpret_cast<float2*>(&out[2 * t]) = make_float2(w1, w2);
    *reinterpret_cast<float2*>(&out[2 * TT + 2 * t]) =
        make_float2((float)i1, (float)i2);

    __shared__ float bins[64];
    bins[lane] = 0.0f;
    __syncthreads();
    atomicAdd(&bins[i1], w1);
    atomicAdd(&bins[i2], w2);
    __syncthreads();
    binpart[(size_t)blockIdx.x * 64 + lane] = bins[lane];
}

// ---------------------------------------------------------------------------
// Kernel C: deterministic tree-sum of per-block bins + EMA update.
__global__ __launch_bounds__(64)
void finalize(const float* __restrict__ binpart, const float* __restrict__ loads,
              float* __restrict__ out) {
    const int e = threadIdx.x;
    float s = 0.0f;
    for (int b = 0; b < 256; ++b) s += binpart[(size_t)b * 64 + e];
    out[4 * TT + e] = 0.9f * loads[e] + 0.1f * (s * (1.0f / 16384.0f));
}

// ---------------------------------------------------------------------------
extern "C" void kernel_launch(void* const* d_in, const int* in_sizes, int n_in,
                              void* d_out, int out_size, void* d_ws, size_t ws_size,
                              hipStream_t stream) {
    const float* x = (const float*)d_in[0];       // [16384, 2048]
    const float* wg = (const float*)d_in[1];      // [2048, 64]
    const float* loads = (const float*)d_in[2];   // [64]
    float* out = (float*)d_out;                   // 2*T + 2*T + 64 floats

    const size_t slice_bytes = (size_t)EE * TT * sizeof(float);  // 4 MiB
    int shift = 3;                                // prefer dsplit = 8
    while (shift > 0 &&
           ws_size < ((size_t)(1 << shift)) * slice_bytes + 256 * 64 * sizeof(float))
        --shift;
    const int dsplit = 1 << shift;

    float* part = (float*)d_ws;                           // [dsplit][E][T]
    float* binpart = part + (size_t)dsplit * EE * TT;     // [256][64]

    hipLaunchKernelGGL(gate_partial, dim3(64 * dsplit), dim3(256), 0, stream,
                       x, wg, part, shift);
    hipLaunchKernelGGL(reduce_topk, dim3(256), dim3(64), 0, stream,
                       part, loads, out, binpart, dsplit);
    hipLaunchKernelGGL(finalize, dim3(1), dim3(64), 0, stream,
                       binpart, loads, out);
}

// Round 2
// 124.036 us; speedup vs baseline: 1.1824x; 1.1824x over previous
//
#include <hip/hip_runtime.h>

#define TT 16384
#define DD 2048
#define EE 64

typedef __attribute__((ext_vector_type(8))) short bf16x8;
typedef __attribute__((ext_vector_type(4))) float f32x4;

__device__ __forceinline__ ushort bf16_rne(float f) {
    unsigned u = __float_as_uint(f);
    return (ushort)((u + 0x7FFFu + ((u >> 16) & 1u)) >> 16);
}
__device__ __forceinline__ float bf16_f32(ushort h) {
    return __uint_as_float(((unsigned)h) << 16);
}

// ---------------------------------------------------------------------------
// Convert W [2048][64] f32 -> W^T hi/lo bf16 [64][2048] (A-operand row-major).
// 512 KB total, L2-resident; coalesced reads, scattered 2B writes (tiny).
__global__ __launch_bounds__(256)
void wconv(const float* __restrict__ wg, ushort* __restrict__ whiT,
           ushort* __restrict__ wloT) {
    int i = (int)blockIdx.x * 8192 + threadIdx.x;
#pragma unroll 8
    for (int j = 0; j < 32; ++j, i += 256) {
        const float f = wg[i];
        const ushort h = bf16_rne(f);
        const ushort l = bf16_rne(f - bf16_f32(h));
        const int k = i >> 6, e = i & 63;
        whiT[e * DD + k] = h;
        wloT[e * DD + k] = l;
    }
}

// ---------------------------------------------------------------------------
// Fused gate GEMM (bf16x3 MFMA) + biased top-2 + softmax + per-block bins.
// A = W^T (64 x 2048, bf16 hi/lo from L2), B = x^T chunk (2048 x 16 tokens).
// mfma_f32_16x16x32_bf16:  A-frag row = lane&15, k = (lane>>4)*8 + j (contig 8)
//                          B-frag col = lane&15 (token), same k
//                          D col = lane&15 (token), row = (lane>>4)*4 + reg.
// Wave = 16 tokens, block = 4 waves = 64 tokens, grid 256 = 1 block/CU.
// No LDS in the main loop, no barriers: x loads stream from HBM/L3, W from L1/L2.
__global__ __launch_bounds__(256)
void gate_fused(const float* __restrict__ x, const ushort* __restrict__ whiT,
                const ushort* __restrict__ wloT, const float* __restrict__ loads,
                float* __restrict__ out, float* __restrict__ binpart) {
    const int tid = threadIdx.x;
    const int lane = tid & 63;
    const int wv = tid >> 6;
    const int col = lane & 15;           // token col within wave / A row within M-tile
    const int kg = (lane >> 4) * 8;      // k-subgroup
    const int tok = (int)blockIdx.x * 64 + wv * 16 + col;

    const float* xr = x + (size_t)tok * DD;
    const ushort* ah = whiT + (size_t)col * DD;
    const ushort* al = wloT + (size_t)col * DD;

    f32x4 acc[4] = {{0,0,0,0},{0,0,0,0},{0,0,0,0},{0,0,0,0}};

    // 2-deep x prefetch (per K-step the wave pulls 2 KB of x; depth 2 gives
    // ~8 KB in flight per CU against the ~9 KB needed at full HBM BW).
    float4 a0 = *(const float4*)(xr + kg);
    float4 b0 = *(const float4*)(xr + kg + 4);
    float4 a1 = *(const float4*)(xr + 32 + kg);
    float4 b1 = *(const float4*)(xr + 32 + kg + 4);

    auto body = [&](int kk, float4 ca, float4 cb) {
        const int k = kk * 32 + kg;
        float cf[8] = {ca.x, ca.y, ca.z, ca.w, cb.x, cb.y, cb.z, cb.w};
        bf16x8 bhi, blo;
#pragma unroll
        for (int j = 0; j < 8; ++j) {
            const ushort h = bf16_rne(cf[j]);
            bhi[j] = (short)h;
            blo[j] = (short)bf16_rne(cf[j] - bf16_f32(h));
        }
#pragma unroll
        for (int m = 0; m < 4; ++m) {
            const bf16x8 fh = *(const bf16x8*)(ah + (size_t)(m * 16) * DD + k);
            const bf16x8 fl = *(const bf16x8*)(al + (size_t)(m * 16) * DD + k);
            acc[m] = __builtin_amdgcn_mfma_f32_16x16x32_bf16(fh, bhi, acc[m], 0, 0, 0);
            acc[m] = __builtin_amdgcn_mfma_f32_16x16x32_bf16(fh, blo, acc[m], 0, 0, 0);
            acc[m] = __builtin_amdgcn_mfma_f32_16x16x32_bf16(fl, bhi, acc[m], 0, 0, 0);
        }
    };

    for (int kk = 0; kk < 64; kk += 2) {
        float4 ca = a0, cb = b0;
        if (kk < 62) {
            a0 = *(const float4*)(xr + (kk + 2) * 32 + kg);
            b0 = *(const float4*)(xr + (kk + 2) * 32 + kg + 4);
        }
        body(kk, ca, cb);
        ca = a1; cb = b1;
        if (kk < 61) {
            a1 = *(const float4*)(xr + (kk + 3) * 32 + kg);
            b1 = *(const float4*)(xr + (kk + 3) * 32 + kg + 4);
        }
        body(kk + 1, ca, cb);
    }

    // ---- top-2 (biased) ------------------------------------------------
    // Lane holds 16 experts for its token: e = m*16 + (lane>>4)*4 + r.
    const int erow = (lane >> 4) * 4;
    float v1 = -3.4e38f, u1 = 0.0f, v2 = -3.4e38f, u2 = 0.0f;
    int i1 = 0x7fffffff, i2 = 0x7fffffff;
#pragma unroll
    for (int m = 0; m < 4; ++m)
#pragma unroll
        for (int r = 0; r < 4; ++r) {
            const int e = m * 16 + erow + r;
            const float u = acc[m][r];
            const float b = u - (loads[e] - 0.015625f) * 2.0f;
            const bool g1 = (b > v1) || (b == v1 && e < i1);
            if (g1) {
                v2 = v1; u2 = u1; i2 = i1;
                v1 = b;  u1 = u;  i1 = e;
            } else if ((b > v2) || (b == v2 && e < i2)) {
                v2 = b; u2 = u; i2 = e;
            }
        }
    // Merge the 4 lanes (xor 16, 32) holding this token's expert quarters.
#pragma unroll
    for (int s = 0; s < 2; ++s) {
        const int mask = 16 << s;
        const float ov1 = __shfl_xor(v1, mask), ou1 = __shfl_xor(u1, mask);
        const float ov2 = __shfl_xor(v2, mask), ou2 = __shfl_xor(u2, mask);
        const int oi1 = __shfl_xor(i1, mask), oi2 = __shfl_xor(i2, mask);
        const bool og = (ov1 > v1) || (ov1 == v1 && oi1 < i1);
        if (og) {
            const bool keep = (v1 > ov2) || (v1 == ov2 && i1 < oi2);
            if (keep) { v2 = v1; u2 = u1; i2 = i1; }
            else      { v2 = ov2; u2 = ou2; i2 = oi2; }
            v1 = ov1; u1 = ou1; i1 = oi1;
        } else if ((ov1 > v2) || (ov1 == v2 && oi1 < i2)) {
            v2 = ov1; u2 = ou1; i2 = oi1;
        }
    }

    __shared__ float bins[64];
    if (tid < 64) bins[tid] = 0.0f;
    __syncthreads();
    if (lane < 16) {
        const float mx = fmaxf(u1, u2);
        const float e1 = __expf(u1 - mx), e2 = __expf(u2 - mx);
        const float w1 = e1 / (e1 + e2), w2 = e2 / (e1 + e2);
        *(float2*)(out + 2 * tok) = make_float2(w1, w2);
        *(float2*)(out + 2 * TT + 2 * tok) = make_float2((float)i1, (float)i2);
        atomicAdd(&bins[i1], w1);
        atomicAdd(&bins[i2], w2);
    }
    __syncthreads();
    if (tid < 64) binpart[(size_t)blockIdx.x * 64 + tid] = bins[tid];
}

// ---------------------------------------------------------------------------
// Sum 256 per-block bins + EMA load update.
__global__ __launch_bounds__(256)
void finalize(const float* __restrict__ binpart, const float* __restrict__ loads,
              float* __restrict__ out) {
    __shared__ float p[256];
    const int e = threadIdx.x & 63, q = threadIdx.x >> 6;
    float s = 0.0f;
#pragma unroll 4
    for (int b = q; b < 256; b += 4) s += binpart[b * 64 + e];
    p[threadIdx.x] = s;
    __syncthreads();
    if (q == 0) {
        const float tot = p[e] + p[64 + e] + p[128 + e] + p[192 + e];
        out[4 * TT + e] = 0.9f * loads[e] + 0.1f * (tot * (1.0f / 16384.0f));
    }
}

// ---------------------------------------------------------------------------
extern "C" void kernel_launch(void* const* d_in, const int* in_sizes, int n_in,
                              void* d_out, int out_size, void* d_ws, size_t ws_size,
                              hipStream_t stream) {
    const float* x = (const float*)d_in[0];      // [16384, 2048]
    const float* wg = (const float*)d_in[1];     // [2048, 64]
    const float* loads = (const float*)d_in[2];  // [64]
    float* out = (float*)d_out;

    ushort* whiT = (ushort*)d_ws;                       // [64][2048] bf16 hi
    ushort* wloT = whiT + (size_t)EE * DD;              // [64][2048] bf16 lo
    float* binpart = (float*)(wloT + (size_t)EE * DD);  // [256][64]

    hipLaunchKernelGGL(wconv, dim3(16), dim3(256), 0, stream, wg, whiT, wloT);
    hipLaunchKernelGGL(gate_fused, dim3(256), dim3(256), 0, stream,
                       x, whiT, wloT, loads, out, binpart);
    hipLaunchKernelGGL(finalize, dim3(1), dim3(256), 0, stream,
                       binpart, loads, out);
}